// Round 1
// 404.287 us; speedup vs baseline: 1.0051x; 1.0051x over previous
//
#include <hip/hip_runtime.h>

// ---------------------------------------------------------------------------
// GCN encoder, bf16 staging + MFMA GEMMs + bpermute-broadcast gather agg.
//   h  = relu(Agg(x@W1) + b1);  [mu|lv] = Agg(h@[Wmu|Wlv]) + bias
// Agg(p)[i] = dinv[i] * ( sum_{e: dst=i} p'[src] + p'[i] ), p' = p*dinv[row]
// dinv[src] is folded into the GEMM epilogue (p' = bf16(acc*dinv), same
// rounding count as before: one bf16 round per term). Agg: 4 nodes/wave,
// 16 lanes x 8ch dwordx4 gather, ds_bpermute broadcast, invalid slots load
// the zeroed row n (+0.0, cache-hot).
// CSR build: LDS radix binning (bucket = dst>>7, 1024 buckets x 128 nodes),
// zero global atomics. Requires n <= 131072 (n = 100000 here).
// ---------------------------------------------------------------------------

#define C_IN  256
#define HID   128
#define C_OUT 64
#define NBUCK 1024
#define P1WGS 256

typedef __attribute__((ext_vector_type(8))) short bf16x8;
typedef __attribute__((ext_vector_type(4))) float f32x4;

__device__ inline unsigned short f2bf(float f) {  // round-to-nearest-even
  unsigned u = __float_as_uint(f);
  unsigned r = u + 0x7FFF + ((u >> 16) & 1);
  return (unsigned short)(r >> 16);
}
__device__ inline float bflo(unsigned v) { return __uint_as_float(v << 16); }
__device__ inline float bfhi(unsigned v) { return __uint_as_float(v & 0xFFFF0000u); }

// ---------------- P1: per-WG bucket histogram (LDS atomics only) -------------
__global__ __launch_bounds__(256) void k_bin_count(const int* __restrict__ dst,
                                                   int* __restrict__ histmat, int E) {
  __shared__ int h[NBUCK];
  int tid = threadIdx.x;
  for (int i = tid; i < NBUCK; i += 256) h[i] = 0;
  __syncthreads();
  for (int e = blockIdx.x * 256 + tid; e < E; e += P1WGS * 256)
    atomicAdd(&h[dst[e] >> 7], 1);
  __syncthreads();
  for (int i = tid; i < NBUCK; i += 256)
    histmat[blockIdx.x * NBUCK + i] = h[i];
}

// ---------------- P2: per-bucket exclusive scan across WGs (in place) --------
__global__ __launch_bounds__(256) void k_col_scan(int* __restrict__ histmat,
                                                  int* __restrict__ bucket_tot) {
  __shared__ int sh[P1WGS];
  int b = blockIdx.x;
  int t = threadIdx.x;
  int v = histmat[t * NBUCK + b];
  sh[t] = v; __syncthreads();
  for (int ofs = 1; ofs < P1WGS; ofs <<= 1) {
    int add = (t >= ofs) ? sh[t - ofs] : 0;
    __syncthreads();
    sh[t] += add;
    __syncthreads();
  }
  histmat[t * NBUCK + b] = sh[t] - v;  // exclusive
  if (t == P1WGS - 1) bucket_tot[b] = sh[t];
}

// ---------------- P3: bucket_start = exclusive scan of bucket_tot ------------
__global__ void k_bucket_scan(const int* __restrict__ bucket_tot,
                              int* __restrict__ bucket_start, int E) {
  __shared__ int sh[NBUCK];
  int t = threadIdx.x;
  int v = bucket_tot[t];
  sh[t] = v; __syncthreads();
  for (int ofs = 1; ofs < NBUCK; ofs <<= 1) {
    int add = (t >= ofs) ? sh[t - ofs] : 0;
    __syncthreads();
    sh[t] += add;
    __syncthreads();
  }
  bucket_start[t] = sh[t] - v;
  if (t == NBUCK - 1) bucket_start[NBUCK] = E;
}

// ---------------- P4: scatter edges into bucket-segmented array --------------
__global__ __launch_bounds__(256) void k_bin_scatter(const int* __restrict__ src,
                                                     const int* __restrict__ dst,
                                                     const int* __restrict__ histmat,
                                                     const int* __restrict__ bucket_start,
                                                     unsigned* __restrict__ binned, int E) {
  __shared__ int cur[NBUCK];
  int tid = threadIdx.x;
  for (int i = tid; i < NBUCK; i += 256)
    cur[i] = bucket_start[i] + histmat[blockIdx.x * NBUCK + i];
  __syncthreads();
  for (int e = blockIdx.x * 256 + tid; e < E; e += P1WGS * 256) {
    int d = dst[e];
    int pos = atomicAdd(&cur[d >> 7], 1);
    binned[pos] = (unsigned)src[e] | ((unsigned)(d & 127) << 17);
  }
}

// ---------------- P5: per-bucket deg/dinv/row_start + CSR fill ---------------
__global__ __launch_bounds__(256) void k_bucket_csr(const unsigned* __restrict__ binned,
                                                    const int* __restrict__ bucket_start,
                                                    int* __restrict__ row_start,
                                                    float* __restrict__ dinv,
                                                    int* __restrict__ csr_src,
                                                    int n, int E) {
  __shared__ int h[128], ls[128], c[128];
  int b = blockIdx.x, t = threadIdx.x;
  int start = bucket_start[b], end = bucket_start[b + 1];
  if (t < 128) h[t] = 0;
  __syncthreads();
  for (int e = start + t; e < end; e += 256)
    atomicAdd(&h[binned[e] >> 17], 1);
  __syncthreads();
  if (t < 128) ls[t] = h[t];
  __syncthreads();
  for (int ofs = 1; ofs < 128; ofs <<= 1) {
    int add = (t < 128 && t >= ofs) ? ls[t - ofs] : 0;
    __syncthreads();
    if (t < 128) ls[t] += add;
    __syncthreads();
  }
  if (t < 128) {
    int excl = ls[t] - h[t];
    ls[t] = excl;
    c[t] = excl;
    int node = b * 128 + t;
    if (node < n) {
      row_start[node] = start + excl;
      dinv[node] = rsqrtf((float)h[t] + 1.0f);
    }
  }
  if (b == 0 && t == 0) row_start[n] = E;
  __syncthreads();
  for (int e = start + t; e < end; e += 256) {
    unsigned v = binned[e];
    int pos = start + atomicAdd(&c[v >> 17], 1);
    csr_src[pos] = (int)(v & 0x1FFFF);
  }
}

// ---------------- weight pre-swizzle + zero-row init -------------------------
// Bswz[s][t][L][j] = bf16( B[s*32 + (L>>4)*8 + j][t*16 + (L&15)] )
__global__ void k_prep(const float* __restrict__ W1, const float* __restrict__ Wmu,
                       const float* __restrict__ Wlv,
                       unsigned short* __restrict__ bswz1,
                       unsigned short* __restrict__ bswz2,
                       unsigned* __restrict__ p1z, unsigned* __restrict__ p2z) {
  int idx = blockIdx.x * 256 + threadIdx.x;
  if (idx < 4096) {            // W1: (256/32)*8*64
    int L = idx & 63, t = (idx >> 6) & 7, s = idx >> 9;
    const float* srcp = W1 + (size_t)(s * 32 + ((L >> 4) << 3)) * 128 + t * 16 + (L & 15);
    unsigned short* dstp = bswz1 + (size_t)idx * 8;
#pragma unroll
    for (int j = 0; j < 8; j++) dstp[j] = f2bf(srcp[(size_t)j * 128]);
  } else if (idx < 6144) {     // [Wmu|Wlv]: (128/32)*8*64
    int id2 = idx - 4096;
    int L = id2 & 63, t = (id2 >> 6) & 7, s = id2 >> 9;
    int nn = t * 16 + (L & 15);
    int k0 = s * 32 + ((L >> 4) << 3);
    const float* W = (nn < C_OUT) ? (Wmu + nn) : (Wlv + (nn - C_OUT));
    unsigned short* dstp = bswz2 + (size_t)id2 * 8;
#pragma unroll
    for (int j = 0; j < 8; j++) dstp[j] = f2bf(W[(size_t)(k0 + j) * C_OUT]);
  } else if (idx < 6208) {     // zero row n of p1 (64 dwords)
    p1z[idx - 6144] = 0u;
  } else if (idx < 6272) {     // zero row n of p2
    p2z[idx - 6208] = 0u;
  }
}

// ---------------- MFMA GEMM: C[M,128](bf16) = (A[M,K] @ B[K,128]) * dinv[row] --
template <typename AT, int K>
__global__ __launch_bounds__(256) void k_gemm_mfma(const AT* __restrict__ A,
                                                   const unsigned short* __restrict__ bswz,
                                                   unsigned short* __restrict__ C,
                                                   const float* __restrict__ dinv,
                                                   int M) {
  constexpr int NS = K / 32;
  int wave = threadIdx.x >> 6, lane = threadIdx.x & 63;
  int m0 = blockIdx.x * 64 + wave * 16;
  int lrow = lane & 15, lq = lane >> 4;
  int arow = m0 + lrow;
  bool rv = arow < M;
  const AT* ap = A + (size_t)(rv ? arow : 0) * K + lq * 8;

  auto loadA = [&](int s) -> bf16x8 {
    if (sizeof(AT) == 4) {
      const float* af = (const float*)ap + s * 32;
      float4 u0 = rv ? *(const float4*)(af) : float4{0, 0, 0, 0};
      float4 u1 = rv ? *(const float4*)(af + 4) : float4{0, 0, 0, 0};
      union { unsigned short us[8]; bf16x8 v; } tmp;
      tmp.us[0] = f2bf(u0.x); tmp.us[1] = f2bf(u0.y);
      tmp.us[2] = f2bf(u0.z); tmp.us[3] = f2bf(u0.w);
      tmp.us[4] = f2bf(u1.x); tmp.us[5] = f2bf(u1.y);
      tmp.us[6] = f2bf(u1.z); tmp.us[7] = f2bf(u1.w);
      return tmp.v;
    } else {
      const unsigned short* ab = (const unsigned short*)ap + s * 32;
      return rv ? *(const bf16x8*)(ab) : (bf16x8)(short)0;
    }
  };

  f32x4 acc[8];
#pragma unroll
  for (int t = 0; t < 8; t++) acc[t] = (f32x4){0.f, 0.f, 0.f, 0.f};

  bf16x8 a_cur = loadA(0);
  bf16x8 b_cur[8];
#pragma unroll
  for (int t = 0; t < 8; t++)
    b_cur[t] = *(const bf16x8*)(bswz + lane * 8 + t * 512);

#pragma unroll
  for (int s = 0; s < NS; ++s) {
    bf16x8 a_nxt = a_cur;
    bf16x8 b_nxt[8];
    if (s + 1 < NS) {
      a_nxt = loadA(s + 1);
      const unsigned short* bp = bswz + (size_t)(s + 1) * 4096 + lane * 8;
#pragma unroll
      for (int t = 0; t < 8; t++) b_nxt[t] = *(const bf16x8*)(bp + t * 512);
    }
#pragma unroll
    for (int t = 0; t < 8; t++)
      acc[t] = __builtin_amdgcn_mfma_f32_16x16x32_bf16(a_cur, b_cur[t], acc[t], 0, 0, 0);
    a_cur = a_nxt;
    if (s + 1 < NS) {
#pragma unroll
      for (int t = 0; t < 8; t++) b_cur[t] = b_nxt[t];
    }
  }
#pragma unroll
  for (int i = 0; i < 4; i++) {
    int rr = m0 + lq * 4 + i;
    if (rr < M) {
      float dsc = dinv[rr];           // fold dinv[src] into staged rows
      unsigned short* cp = C + (size_t)rr * 128 + lrow;
#pragma unroll
      for (int t = 0; t < 8; t++) cp[t * 16] = f2bf(acc[t][i] * dsc);
    }
  }
}

// ---------------- gather aggregation: 4 nodes/wave, dwordx4, bpermute --------
// p has n+1 rows of 128 bf16; row n is all-zero (safe target for idle slots).
#define AGG_V4_BODY                                                                 \
  int tid = threadIdx.x;                                                            \
  int wid4 = blockIdx.x * 4 + (tid >> 6); /* wave id, 4 waves/WG */                 \
  int lane = tid & 63;                                                              \
  int li = lane & 15;                                                               \
  int node = (wid4 << 2) + (lane >> 4);                                             \
  int rs = 0, re = -1;                                                              \
  if (node < n) { rs = row_start[node]; re = row_start[node + 1]; }                 \
  int mc = re - rs + 1; /* edges incl. self */                                      \
  mc = max(mc, __shfl_xor(mc, 16, 64));                                             \
  mc = max(mc, __shfl_xor(mc, 32, 64));                                             \
  int maxcnt = __builtin_amdgcn_readfirstlane(mc);                                  \
  const char* pb = (const char*)p;                                                  \
  unsigned loff = (unsigned)(li << 4);                                              \
  int vb = (lane & 48) << 2; /* byte idx of group base lane for bpermute */         \
  float acc[8];                                                                     \
  _Pragma("unroll")                                                                 \
  for (int j = 0; j < 8; ++j) acc[j] = 0.f;                                         \
  for (int t0 = 0; t0 < maxcnt; t0 += 16) {                                         \
    int s = rs + t0 + li;                                                           \
    int sl = n; /* zero row */                                                      \
    if (s < re) sl = csr[s];                                                        \
    else if (s == re) sl = node; /* self edge */                                    \
    int km = maxcnt - t0; if (km > 16) km = 16;                                     \
    for (int k = 0; k < km; k += 4) {                                               \
      int sk0 = __builtin_amdgcn_ds_bpermute(vb + ((k + 0) << 2), sl);              \
      int sk1 = __builtin_amdgcn_ds_bpermute(vb + ((k + 1) << 2), sl);              \
      int sk2 = __builtin_amdgcn_ds_bpermute(vb + ((k + 2) << 2), sl);              \
      int sk3 = __builtin_amdgcn_ds_bpermute(vb + ((k + 3) << 2), sl);              \
      uint4 v0 = *(const uint4*)(pb + ((((unsigned)sk0) << 8) + loff));             \
      uint4 v1 = *(const uint4*)(pb + ((((unsigned)sk1) << 8) + loff));             \
      uint4 v2 = *(const uint4*)(pb + ((((unsigned)sk2) << 8) + loff));             \
      uint4 v3 = *(const uint4*)(pb + ((((unsigned)sk3) << 8) + loff));             \
      acc[0] += bflo(v0.x); acc[1] += bfhi(v0.x);                                   \
      acc[2] += bflo(v0.y); acc[3] += bfhi(v0.y);                                   \
      acc[4] += bflo(v0.z); acc[5] += bfhi(v0.z);                                   \
      acc[6] += bflo(v0.w); acc[7] += bfhi(v0.w);                                   \
      acc[0] += bflo(v1.x); acc[1] += bfhi(v1.x);                                   \
      acc[2] += bflo(v1.y); acc[3] += bfhi(v1.y);                                   \
      acc[4] += bflo(v1.z); acc[5] += bfhi(v1.z);                                   \
      acc[6] += bflo(v1.w); acc[7] += bfhi(v1.w);                                   \
      acc[0] += bflo(v2.x); acc[1] += bfhi(v2.x);                                   \
      acc[2] += bflo(v2.y); acc[3] += bfhi(v2.y);                                   \
      acc[4] += bflo(v2.z); acc[5] += bfhi(v2.z);                                   \
      acc[6] += bflo(v2.w); acc[7] += bfhi(v2.w);                                   \
      acc[0] += bflo(v3.x); acc[1] += bfhi(v3.x);                                   \
      acc[2] += bflo(v3.y); acc[3] += bfhi(v3.y);                                   \
      acc[4] += bflo(v3.z); acc[5] += bfhi(v3.z);                                   \
      acc[6] += bflo(v3.w); acc[7] += bfhi(v3.w);                                   \
    }                                                                               \
  }

__global__ __launch_bounds__(256) void k_agg_relu_bf(
    const unsigned short* __restrict__ p, const float* __restrict__ dinv,
    const int* __restrict__ row_start, const int* __restrict__ csr,
    const float* __restrict__ bias, unsigned short* __restrict__ h, int n) {
  AGG_V4_BODY
  if (node < n) {
    float di = dinv[node];
    float4 ba = *(const float4*)(bias + (li << 3));
    float4 bb = *(const float4*)(bias + (li << 3) + 4);
    float r0 = fmaxf(acc[0] * di + ba.x, 0.f);
    float r1 = fmaxf(acc[1] * di + ba.y, 0.f);
    float r2 = fmaxf(acc[2] * di + ba.z, 0.f);
    float r3 = fmaxf(acc[3] * di + ba.w, 0.f);
    float r4 = fmaxf(acc[4] * di + bb.x, 0.f);
    float r5 = fmaxf(acc[5] * di + bb.y, 0.f);
    float r6 = fmaxf(acc[6] * di + bb.z, 0.f);
    float r7 = fmaxf(acc[7] * di + bb.w, 0.f);
    uint4 u;
    u.x = (unsigned)f2bf(r0) | ((unsigned)f2bf(r1) << 16);
    u.y = (unsigned)f2bf(r2) | ((unsigned)f2bf(r3) << 16);
    u.z = (unsigned)f2bf(r4) | ((unsigned)f2bf(r5) << 16);
    u.w = (unsigned)f2bf(r6) | ((unsigned)f2bf(r7) << 16);
    *(uint4*)((char*)h + (((size_t)node) << 8) + loff) = u;
  }
}

__global__ __launch_bounds__(256) void k_agg_out_bf(
    const unsigned short* __restrict__ p, const float* __restrict__ dinv,
    const int* __restrict__ row_start, const int* __restrict__ csr,
    const float* __restrict__ bmu, const float* __restrict__ blv,
    float* __restrict__ out, int n) {
  AGG_V4_BODY
  if (node < n) {
    float di = dinv[node];
    const float* bp = (li < 8) ? (bmu + (li << 3)) : (blv + ((li - 8) << 3));
    float* op = (li < 8) ? (out + (size_t)node * C_OUT + (li << 3))
                         : (out + (size_t)(n + node) * C_OUT + ((li - 8) << 3));
    float4 b0 = *(const float4*)(bp);
    float4 b1 = *(const float4*)(bp + 4);
    float4 o0 = {acc[0] * di + b0.x, acc[1] * di + b0.y,
                 acc[2] * di + b0.z, acc[3] * di + b0.w};
    float4 o1 = {acc[4] * di + b1.x, acc[5] * di + b1.y,
                 acc[6] * di + b1.z, acc[7] * di + b1.w};
    *(float4*)op = o0;
    *(float4*)(op + 4) = o1;
  }
}

// ---------------------------------------------------------------------------
extern "C" void kernel_launch(void* const* d_in, const int* in_sizes, int n_in,
                              void* d_out, int out_size, void* d_ws, size_t ws_size,
                              hipStream_t stream) {
  const float* x   = (const float*)d_in[0];
  const int*   ei  = (const int*)d_in[1];   // int32 on the wire (JAX x64 off)
  const float* W1  = (const float*)d_in[2];
  const float* b1  = (const float*)d_in[3];
  const float* Wmu = (const float*)d_in[4];
  const float* bmu = (const float*)d_in[5];
  const float* Wlv = (const float*)d_in[6];
  const float* blv = (const float*)d_in[7];
  float* out = (float*)d_out;

  const int n = in_sizes[0] / C_IN;
  const int E = in_sizes[1] / 2;
  const int* src = ei;
  const int* dst = ei + E;

  char* w = (char*)d_ws;
  auto alloc = [&](size_t bytes) -> void* {
    void* pp = (void*)w;
    w += (bytes + 255) & ~(size_t)255;
    return pp;
  };
  float*          dinv       = (float*)alloc((size_t)n * 4);
  int*            row_start  = (int*)alloc((size_t)(n + 1) * 4);
  int*            histmat    = (int*)alloc((size_t)P1WGS * NBUCK * 4);
  int*            bucket_tot = (int*)alloc((size_t)NBUCK * 4);
  int*            bucket_st  = (int*)alloc((size_t)(NBUCK + 1) * 4);
  unsigned*       binned     = (unsigned*)alloc((size_t)E * 4);
  int*            csr_src    = (int*)alloc((size_t)E * 4);
  unsigned short* bswz1      = (unsigned short*)alloc((size_t)C_IN * 128 * 2);
  unsigned short* bswz2      = (unsigned short*)alloc((size_t)HID * 128 * 2);
  unsigned short* p1         = (unsigned short*)alloc((size_t)(n + 1) * 128 * 2);
  unsigned short* hbuf       = (unsigned short*)alloc((size_t)n * 128 * 2);
  unsigned short* p2         = (unsigned short*)alloc((size_t)(n + 1) * 128 * 2);
  (void)ws_size; (void)n_in; (void)out_size;

  const int TB = 256;
  const int gemm_bks = (n + 63) / 64;
  const int agg_bks = (n + 15) / 16;          // 4 nodes/wave, 4 waves/WG
  const int nbk_csr = (n + 127) / 128;        // buckets w/ valid nodes

  // ---- CSR build: LDS radix binning, no global atomics ----
  k_bin_count<<<P1WGS, TB, 0, stream>>>(dst, histmat, E);
  k_col_scan<<<NBUCK, TB, 0, stream>>>(histmat, bucket_tot);
  k_bucket_scan<<<1, NBUCK, 0, stream>>>(bucket_tot, bucket_st, E);
  k_bin_scatter<<<P1WGS, TB, 0, stream>>>(src, dst, histmat, bucket_st, binned, E);
  k_bucket_csr<<<nbk_csr, TB, 0, stream>>>(binned, bucket_st, row_start, dinv,
                                           csr_src, n, E);

  // ---- weight pre-swizzle + zero rows n of p1/p2 ----
  k_prep<<<25, 256, 0, stream>>>(W1, Wmu, Wlv, bswz1, bswz2,
                                 (unsigned*)(p1 + (size_t)n * 128),
                                 (unsigned*)(p2 + (size_t)n * 128));

  // ---- layer 1 ----
  k_gemm_mfma<float, C_IN><<<gemm_bks, TB, 0, stream>>>(x, bswz1, p1, dinv, n);
  k_agg_relu_bf<<<agg_bks, TB, 0, stream>>>(p1, dinv, row_start, csr_src, b1, hbuf, n);

  // ---- layer 2+3 fused ----
  k_gemm_mfma<unsigned short, HID><<<gemm_bks, TB, 0, stream>>>(hbuf, bswz2, p2, dinv, n);
  k_agg_out_bf<<<agg_bks, TB, 0, stream>>>(p2, dinv, row_start, csr_src, bmu, blv, out, n);
}